// Round 1
// baseline (103.878 us; speedup 1.0000x reference)
//
#include <hip/hip_runtime.h>
#include <hip/hip_bf16.h>
#include <math.h>

#define B_ 256
#define D_ 512
#define C_ 100000

#define SCALE_  64.0f
#define ALPHA_  1.2f
// THRESH = cos(pi - 0.5), MM = sin(pi - 0.5) * 0.5
#define THRESH_ (-0.8775825618903728f)
#define MM_     (0.23971276930210156f)
#define COSM_   (0.8775825618903728f)   // cos(0.5)
#define SINM_   (0.4794255386042030f)   // sin(0.5)

typedef __bf16 bf16x8 __attribute__((ext_vector_type(8)));
typedef __bf16 bf16x4 __attribute__((ext_vector_type(4)));
typedef float  f32x4  __attribute__((ext_vector_type(4)));

// ---------------------------------------------------------------------------
// prep: normalize input rows -> bf16 xn; compute a_lb per row (f32 path);
// canonicalize labels (robust to int64-vs-int32 storage).
// grid: 256 blocks x 64 threads (1 wave per input row)
// ---------------------------------------------------------------------------
__global__ void prep_kernel(const float* __restrict__ inp,
                            const int* __restrict__ lab_raw,
                            const float* __restrict__ weight,
                            __bf16* __restrict__ xn,
                            float* __restrict__ a_lb,
                            int* __restrict__ lab32) {
    const int b = blockIdx.x;
    const int l = threadIdx.x;   // 0..63

    // int64 labels (little-endian) have all-zero high words; int32 random
    // labels in [0,100000) essentially never have 8 zeros at odd slots.
    const bool is64 = (lab_raw[1] == 0) & (lab_raw[3] == 0) & (lab_raw[5] == 0) &
                      (lab_raw[7] == 0) & (lab_raw[9] == 0) & (lab_raw[11] == 0) &
                      (lab_raw[13] == 0) & (lab_raw[15] == 0);
    const int lab = is64 ? lab_raw[2 * b] : lab_raw[b];

    const float* ip = inp + b * D_ + l * 8;
    f32x4 v0 = *(const f32x4*)ip;
    f32x4 v1 = *(const f32x4*)(ip + 4);
    float ss = v0.x * v0.x + v0.y * v0.y + v0.z * v0.z + v0.w * v0.w +
               v1.x * v1.x + v1.y * v1.y + v1.z * v1.z + v1.w * v1.w;
#pragma unroll
    for (int m = 1; m < 64; m <<= 1) ss += __shfl_xor(ss, m);
    const float ninv = 1.0f / fmaxf(sqrtf(ss), 1e-12f);

    float xf[8] = {v0.x * ninv, v0.y * ninv, v0.z * ninv, v0.w * ninv,
                   v1.x * ninv, v1.y * ninv, v1.z * ninv, v1.w * ninv};
    bf16x8 xv;
#pragma unroll
    for (int i = 0; i < 8; ++i) xv[i] = (__bf16)xf[i];
    *(bf16x8*)(xn + b * D_ + l * 8) = xv;

    // target-class cosine in f32
    const float* wp = weight + (size_t)lab * D_ + l * 8;
    f32x4 w0 = *(const f32x4*)wp;
    f32x4 w1 = *(const f32x4*)(wp + 4);
    float wss = w0.x * w0.x + w0.y * w0.y + w0.z * w0.z + w0.w * w0.w +
                w1.x * w1.x + w1.y * w1.y + w1.z * w1.z + w1.w * w1.w;
    float dp = xf[0] * w0.x + xf[1] * w0.y + xf[2] * w0.z + xf[3] * w0.w +
               xf[4] * w1.x + xf[5] * w1.y + xf[6] * w1.z + xf[7] * w1.w;
#pragma unroll
    for (int m = 1; m < 64; m <<= 1) {
        wss += __shfl_xor(wss, m);
        dp  += __shfl_xor(dp, m);
    }
    if (l == 0) {
        const float cos_lb = dp / fmaxf(sqrtf(wss), 1e-12f);
        const float ccl = fminf(fmaxf(cos_lb, -1.0f), 1.0f);
        const float s = sqrtf(fmaxf(0.0f, 1.0f - ccl * ccl));
        const float a1 = ccl * COSM_ - s * SINM_;   // cos(acos(c) + margin)
        a_lb[b] = (cos_lb > THRESH_) ? a1 : (cos_lb - MM_);
        lab32[b] = lab;
    }
}

// ---------------------------------------------------------------------------
// main GEMM + epilogue. Block = full M=256 x BN=128 cols, BK=64, 512 threads
// (8 waves, each 64x64 = 4x4 MFMA frags). Weight row norms fused into staging.
// ---------------------------------------------------------------------------
#define BN 128
#define BK 64

__global__ __launch_bounds__(512)
void gemm_kernel(const __bf16* __restrict__ xn,
                 const float* __restrict__ weight,
                 const float* __restrict__ a_lb,
                 const int* __restrict__ lab32,
                 float* __restrict__ out) {
    __shared__ __align__(16) char aT[B_ * BK * 2];   // 32 KiB
    __shared__ __align__(16) char wT[BN * BK * 2];   // 16 KiB
    __shared__ float wssq[BN];

    const int tid  = threadIdx.x;
    const int lane = tid & 63;
    const int wid  = tid >> 6;
    const int wm   = wid >> 1;     // 0..3 : 64-row slice
    const int wn   = wid & 1;      // 0..1 : 64-col slice
    const int n0   = blockIdx.x * BN;

    f32x4 acc[4][4] = {};
    float wss[4] = {0.f, 0.f, 0.f, 0.f};

    const int wrow = tid >> 4;         // 0..31 (weight staging row group)
    const int wc4  = (tid & 15) * 4;   // f32 col offset in K-tile
    const int arow = tid >> 3;         // 0..63 (A staging row group)
    const int acg  = (tid & 7) * 8;    // bf16 col group

    for (int kt = 0; kt < D_ / BK; ++kt) {
        const int k0 = kt * BK;
        __syncthreads();
        // stage A (xn): 256x64 bf16, XOR-swizzled
#pragma unroll
        for (int r = 0; r < 4; ++r) {
            const int row = arow + r * 64;
            uint4 v = *(const uint4*)(xn + row * D_ + k0 + acg);
            int off = (row * BK + acg) * 2;
            off ^= (row & 7) << 4;
            *(uint4*)(aT + off) = v;
        }
        // stage W: 128x64 f32 -> bf16, XOR-swizzled; fuse row sum-of-squares
#pragma unroll
        for (int r = 0; r < 4; ++r) {
            const int row = wrow + r * 32;
            int g = n0 + row;
            g = (g < C_) ? g : (C_ - 1);
            f32x4 v = *(const f32x4*)(weight + (size_t)g * D_ + k0 + wc4);
            wss[r] += v.x * v.x + v.y * v.y + v.z * v.z + v.w * v.w;
            bf16x4 h;
            h[0] = (__bf16)v.x; h[1] = (__bf16)v.y;
            h[2] = (__bf16)v.z; h[3] = (__bf16)v.w;
            int off = (row * BK + wc4) * 2;
            off ^= (row & 7) << 4;
            *(bf16x4*)(wT + off) = h;
        }
        __syncthreads();

        const int lr = lane & 15;
        const int lk = (lane >> 4) * 8;
#pragma unroll
        for (int ks = 0; ks < 2; ++ks) {
            bf16x8 af[4], bfr[4];
#pragma unroll
            for (int m = 0; m < 4; ++m) {
                const int row = wm * 64 + m * 16 + lr;
                int off = (row * BK + ks * 32 + lk) * 2;
                off ^= (row & 7) << 4;
                af[m] = *(const bf16x8*)(aT + off);
            }
#pragma unroll
            for (int n = 0; n < 4; ++n) {
                const int row = wn * 64 + n * 16 + lr;
                int off = (row * BK + ks * 32 + lk) * 2;
                off ^= (row & 7) << 4;
                bfr[n] = *(const bf16x8*)(wT + off);
            }
#pragma unroll
            for (int m = 0; m < 4; ++m)
#pragma unroll
                for (int n = 0; n < 4; ++n)
                    acc[m][n] = __builtin_amdgcn_mfma_f32_16x16x32_bf16(
                        af[m], bfr[n], acc[m][n], 0, 0, 0);
        }
    }

    // finish fused weight-row norms: reduce across the 16 staging lanes/row
#pragma unroll
    for (int r = 0; r < 4; ++r) {
        float s = wss[r];
        s += __shfl_xor(s, 1);
        s += __shfl_xor(s, 2);
        s += __shfl_xor(s, 4);
        s += __shfl_xor(s, 8);
        if ((tid & 15) == 0) wssq[wrow + r * 32] = s;
    }
    __syncthreads();

    // epilogue: cos -> gaussian-reweighted logits
    float al_r[16];
    int   lb_r[16];
    const int rb0 = wm * 64 + ((lane >> 4) << 2);
#pragma unroll
    for (int m = 0; m < 4; ++m)
#pragma unroll
        for (int j = 0; j < 4; ++j) {
            const int b = rb0 + m * 16 + j;
            al_r[m * 4 + j] = a_lb[b];
            lb_r[m * 4 + j] = lab32[b];
        }

#pragma unroll
    for (int n = 0; n < 4; ++n) {
        const int ln = wn * 64 + n * 16 + (lane & 15);
        const int c = n0 + ln;
        const float winv = 1.0f / fmaxf(sqrtf(wssq[ln]), 1e-12f);
        const bool ok = (c < C_);
#pragma unroll
        for (int m = 0; m < 4; ++m)
#pragma unroll
            for (int j = 0; j < 4; ++j) {
                const int b = rb0 + m * 16 + j;
                const float al = al_r[m * 4 + j];
                const float cosv = acc[m][n][j] * winv;
                const float d = cosv - al;
                const float t = ALPHA_ * __expf(-0.5f * d * d);  // SIGMA = 2
                const float o = (c == lb_r[m * 4 + j]) ? al : (t * cosv + t - 1.0f);
                if (ok) out[(size_t)b * C_ + c] = SCALE_ * o;
            }
    }
}

extern "C" void kernel_launch(void* const* d_in, const int* in_sizes, int n_in,
                              void* d_out, int out_size, void* d_ws, size_t ws_size,
                              hipStream_t stream) {
    const float* inp = (const float*)d_in[0];
    const int*   lab = (const int*)d_in[1];
    const float* w   = (const float*)d_in[2];
    float* out = (float*)d_out;

    char* ws = (char*)d_ws;
    __bf16* xn   = (__bf16*)ws;                       // 256*512*2 = 262144 B
    float*  a_lb = (float*)(ws + 262144);             // 1 KiB
    int*    l32  = (int*)(ws + 262144 + 1024);        // 1 KiB

    prep_kernel<<<B_, 64, 0, stream>>>(inp, lab, w, xn, a_lb, l32);
    gemm_kernel<<<(C_ + BN - 1) / BN, 512, 0, stream>>>(xn, w, a_lb, l32, out);
}

// Round 2
// 88.880 us; speedup vs baseline: 1.1687x; 1.1687x over previous
//
#include <hip/hip_runtime.h>
#include <hip/hip_bf16.h>
#include <math.h>

#define B_ 256
#define D_ 512
#define C_ 100000

#define SCALE_  64.0f
#define ALPHA_  1.2f
// THRESH = cos(pi - 0.5), MM = sin(pi - 0.5) * 0.5
#define THRESH_ (-0.8775825618903728f)
#define MM_     (0.23971276930210156f)
#define COSM_   (0.8775825618903728f)   // cos(0.5)
#define SINM_   (0.4794255386042030f)   // sin(0.5)

typedef __bf16 bf16x8 __attribute__((ext_vector_type(8)));
typedef __bf16 bf16x4 __attribute__((ext_vector_type(4)));
typedef float  f32x4  __attribute__((ext_vector_type(4)));

// ---------------------------------------------------------------------------
// prep: normalize input rows -> bf16 stored in MFMA-A-frag-linear layout
// (16x32 tiles, lane-major: tile_idx*1024 + frag_lane*16). Also a_lb + labels.
// grid: 256 blocks x 64 threads (1 wave per input row)
// ---------------------------------------------------------------------------
__global__ void prep_kernel(const float* __restrict__ inp,
                            const int* __restrict__ lab_raw,
                            const float* __restrict__ weight,
                            __bf16* __restrict__ xnf,
                            float* __restrict__ a_lb,
                            int* __restrict__ lab32) {
    const int b = blockIdx.x;
    const int l = threadIdx.x;   // 0..63  (covers cols l*8 .. l*8+7)

    // int64 labels (little-endian) have all-zero high words.
    const bool is64 = (lab_raw[1] == 0) & (lab_raw[3] == 0) & (lab_raw[5] == 0) &
                      (lab_raw[7] == 0) & (lab_raw[9] == 0) & (lab_raw[11] == 0) &
                      (lab_raw[13] == 0) & (lab_raw[15] == 0);
    const int lab = is64 ? lab_raw[2 * b] : lab_raw[b];

    const float* ip = inp + b * D_ + l * 8;
    f32x4 v0 = *(const f32x4*)ip;
    f32x4 v1 = *(const f32x4*)(ip + 4);
    float ss = v0.x * v0.x + v0.y * v0.y + v0.z * v0.z + v0.w * v0.w +
               v1.x * v1.x + v1.y * v1.y + v1.z * v1.z + v1.w * v1.w;
#pragma unroll
    for (int m = 1; m < 64; m <<= 1) ss += __shfl_xor(ss, m);
    const float ninv = 1.0f / fmaxf(sqrtf(ss), 1e-12f);

    float xf[8] = {v0.x * ninv, v0.y * ninv, v0.z * ninv, v0.w * ninv,
                   v1.x * ninv, v1.y * ninv, v1.z * ninv, v1.w * ninv};
    bf16x8 xv;
#pragma unroll
    for (int i = 0; i < 8; ++i) xv[i] = (__bf16)xf[i];

    // frag-linear store: tile (16 rows x 32 cols) = 1024 B, lane holds
    // row (l&15), cols (lane>>4)*8. This row b, col l*8 -> frag lane:
    const int tile_idx = (b >> 4) * 16 + (l >> 2);           // 16 tile-cols
    const int lf = (b & 15) + ((l & 3) << 4);
    *(bf16x8*)((char*)xnf + tile_idx * 1024 + lf * 16) = xv;

    // target-class cosine in f32
    const float* wp = weight + (size_t)lab * D_ + l * 8;
    f32x4 w0 = *(const f32x4*)wp;
    f32x4 w1 = *(const f32x4*)(wp + 4);
    float wss = w0.x * w0.x + w0.y * w0.y + w0.z * w0.z + w0.w * w0.w +
                w1.x * w1.x + w1.y * w1.y + w1.z * w1.z + w1.w * w1.w;
    float dp = xf[0] * w0.x + xf[1] * w0.y + xf[2] * w0.z + xf[3] * w0.w +
               xf[4] * w1.x + xf[5] * w1.y + xf[6] * w1.z + xf[7] * w1.w;
#pragma unroll
    for (int m = 1; m < 64; m <<= 1) {
        wss += __shfl_xor(wss, m);
        dp  += __shfl_xor(dp, m);
    }
    if (l == 0) {
        const float cos_lb = dp / fmaxf(sqrtf(wss), 1e-12f);
        const float ccl = fminf(fmaxf(cos_lb, -1.0f), 1.0f);
        const float s = sqrtf(fmaxf(0.0f, 1.0f - ccl * ccl));
        const float a1 = ccl * COSM_ - s * SINM_;   // cos(acos(c) + margin)
        a_lb[b] = (cos_lb > THRESH_) ? a1 : (cos_lb - MM_);
        lab32[b] = lab;
    }
}

// ---------------------------------------------------------------------------
// GEMM + epilogue. Block = M=256 x BN=64, 256 threads (4 waves, each 64x64).
// A frags loaded directly from frag-linear xnf (L2-resident, 1 coalesced
// dwordx4 per frag). W reg-prefetched one K-step ahead (loads fly under MFMA),
// converted f32->bf16 into XOR-swizzled LDS; row norms fused into staging.
// ---------------------------------------------------------------------------
#define BN 64
#define BK 64

__global__ __launch_bounds__(256, 3)
void gemm_kernel(const __bf16* __restrict__ xnf,
                 const float* __restrict__ weight,
                 const float* __restrict__ a_lb,
                 const int* __restrict__ lab32,
                 float* __restrict__ out) {
    __shared__ __align__(16) char wT[BN * BK * 2];   // 8 KiB
    __shared__ float wssq[BN];

    const int tid  = threadIdx.x;
    const int lane = tid & 63;
    const int wm   = tid >> 6;     // 0..3 : 64-row slice of A
    const int n0   = blockIdx.x * BN;

    f32x4 acc[4][4] = {};
    float wss = 0.0f;

    // W staging: thread t owns row t>>2, 16 f32 cols starting (t&3)*16
    const int wrow = tid >> 2;           // 0..63
    const int wc   = (tid & 3) * 16;     // f32 col base
    int grow = n0 + wrow;
    grow = (grow < C_) ? grow : (C_ - 1);
    const float* wbase = weight + (size_t)grow * D_ + wc;

    f32x4 wpre[4];
#pragma unroll
    for (int i = 0; i < 4; ++i) wpre[i] = *(const f32x4*)(wbase + i * 4);

    for (int kt = 0; kt < D_ / BK; ++kt) {
        if (kt) __syncthreads();   // previous MFMA phase done reading wT
        // convert + sumsq + swizzled ds_write (16 f32 -> 2x bf16x8)
        bf16x8 h0, h1;
#pragma unroll
        for (int i = 0; i < 4; ++i) {
            f32x4 v = wpre[i];
            wss += v.x * v.x + v.y * v.y + v.z * v.z + v.w * v.w;
            if (i < 2) {
                h0[i * 4 + 0] = (__bf16)v.x; h0[i * 4 + 1] = (__bf16)v.y;
                h0[i * 4 + 2] = (__bf16)v.z; h0[i * 4 + 3] = (__bf16)v.w;
            } else {
                h1[(i - 2) * 4 + 0] = (__bf16)v.x; h1[(i - 2) * 4 + 1] = (__bf16)v.y;
                h1[(i - 2) * 4 + 2] = (__bf16)v.z; h1[(i - 2) * 4 + 3] = (__bf16)v.w;
            }
        }
        {
            int off0 = wrow * (BK * 2) + wc * 2;
            int off1 = off0 + 16;
            off0 ^= (wrow & 7) << 4;
            off1 ^= (wrow & 7) << 4;
            *(bf16x8*)(wT + off0) = h0;
            *(bf16x8*)(wT + off1) = h1;
        }
        __syncthreads();

        // prefetch next K-step's W — overlaps the MFMA phase below
        if (kt < D_ / BK - 1) {
            const float* p = wbase + (kt + 1) * BK;
#pragma unroll
            for (int i = 0; i < 4; ++i) wpre[i] = *(const f32x4*)(p + i * 4);
        }

        // A frags direct from global (frag-linear, L2-hit)
        bf16x8 af[2][4];
#pragma unroll
        for (int ks = 0; ks < 2; ++ks)
#pragma unroll
            for (int m = 0; m < 4; ++m) {
                const int tile = (wm * 4 + m) * 16 + kt * 2 + ks;
                af[ks][m] = *(const bf16x8*)((const char*)xnf + tile * 1024 + lane * 16);
            }

#pragma unroll
        for (int ks = 0; ks < 2; ++ks) {
            bf16x8 bfr[4];
#pragma unroll
            for (int n = 0; n < 4; ++n) {
                const int row = n * 16 + (lane & 15);
                int off = row * (BK * 2) + ks * 64 + (lane >> 4) * 16;
                off ^= (row & 7) << 4;
                bfr[n] = *(const bf16x8*)(wT + off);
            }
#pragma unroll
            for (int m = 0; m < 4; ++m)
#pragma unroll
                for (int n = 0; n < 4; ++n)
                    acc[m][n] = __builtin_amdgcn_mfma_f32_16x16x32_bf16(
                        af[ks][m], bfr[n], acc[m][n], 0, 0, 0);
        }
    }

    // finish fused weight-row norms (reduce over the 4 staging lanes per row)
    {
        float s = wss;
        s += __shfl_xor(s, 1);
        s += __shfl_xor(s, 2);
        if ((tid & 3) == 0) wssq[wrow] = s;
    }
    __syncthreads();

    // epilogue
    float al_r[16];
    int   lb_r[16];
    const int rb0 = wm * 64 + ((lane >> 4) << 2);
#pragma unroll
    for (int m = 0; m < 4; ++m)
#pragma unroll
        for (int j = 0; j < 4; ++j) {
            const int b = rb0 + m * 16 + j;
            al_r[m * 4 + j] = a_lb[b];
            lb_r[m * 4 + j] = lab32[b];
        }

#pragma unroll
    for (int n = 0; n < 4; ++n) {
        const int ln = n * 16 + (lane & 15);
        const int c = n0 + ln;
        const float winv = 1.0f / fmaxf(sqrtf(wssq[ln]), 1e-12f);
        const bool ok = (c < C_);
#pragma unroll
        for (int m = 0; m < 4; ++m)
#pragma unroll
            for (int j = 0; j < 4; ++j) {
                const int b = rb0 + m * 16 + j;
                const float al = al_r[m * 4 + j];
                const float cosv = acc[m][n][j] * winv;
                const float d = cosv - al;
                const float t = ALPHA_ * __expf(-0.5f * d * d);  // SIGMA = 2
                const float o = (c == lb_r[m * 4 + j]) ? al : (t * cosv + t - 1.0f);
                if (ok) out[(size_t)b * C_ + c] = SCALE_ * o;
            }
    }
}

extern "C" void kernel_launch(void* const* d_in, const int* in_sizes, int n_in,
                              void* d_out, int out_size, void* d_ws, size_t ws_size,
                              hipStream_t stream) {
    const float* inp = (const float*)d_in[0];
    const int*   lab = (const int*)d_in[1];
    const float* w   = (const float*)d_in[2];
    float* out = (float*)d_out;

    char* ws = (char*)d_ws;
    __bf16* xnf  = (__bf16*)ws;                       // 256*512*2 = 262144 B
    float*  a_lb = (float*)(ws + 262144);             // 1 KiB
    int*    l32  = (int*)(ws + 262144 + 1024);        // 1 KiB

    prep_kernel<<<B_, 64, 0, stream>>>(inp, lab, w, xnf, a_lb, l32);
    gemm_kernel<<<(C_ + BN - 1) / BN, 256, 0, stream>>>(xnf, w, a_lb, l32, out);
}